// Round 1
// baseline (285.368 us; speedup 1.0000x reference)
//
#include <hip/hip_runtime.h>
#include <math.h>

// Problem constants (T=4, B=2 -> TB=8)
#define TBDIM 8
#define CDIM  512
#define NDIM  512
#define HDIM  16
#define DDIM  32

// ---------------------------------------------------------------------------
// GEMM + BN + LIF:
//   z[tb][o][n]   = sum_c W[o][c] * X[tb][c][n]
//   out[tb][o][n] = (z*inv[o] + (beta[o]-mean[o]*inv[o]) >= 2) ? 1 : 0
// 64x64 output tile per 256-thread block, 4x4 microtile/thread, K-chunk 16.
// ---------------------------------------------------------------------------
__global__ __launch_bounds__(256) void gemm_bn_lif(
    const float* __restrict__ X, const float* __restrict__ W,
    const float* __restrict__ gamma, const float* __restrict__ beta,
    const float* __restrict__ mean, const float* __restrict__ var,
    float* __restrict__ out)
{
    const int tb = blockIdx.z;
    const int n0 = blockIdx.x * 64;
    const int o0 = blockIdx.y * 64;
    const int t  = threadIdx.x;

    __shared__ float Ws[16][64];   // Ws[k][o]  (W tile transposed)
    __shared__ float Xs[16][64];   // Xs[k][n]

    const int ty = t >> 4;   // 0..15  (o microtile row)
    const int tx = t & 15;   // 0..15  (n microtile col)

    // load mappings
    const int lw_o = t >> 2;          // 0..63
    const int lw_k = (t & 3) << 2;    // 0,4,8,12
    const int lx_k = t >> 4;          // 0..15
    const int lx_n = (t & 15) << 2;   // 0..60

    const float* Xbase = X + (size_t)tb * CDIM * NDIM;

    float acc[4][4];
    #pragma unroll
    for (int i = 0; i < 4; ++i)
        #pragma unroll
        for (int j = 0; j < 4; ++j) acc[i][j] = 0.0f;

    for (int c0 = 0; c0 < CDIM; c0 += 16) {
        // stage W tile (transposed) and X tile
        const float4 w4 = *(const float4*)(W + (size_t)(o0 + lw_o) * CDIM + c0 + lw_k);
        Ws[lw_k + 0][lw_o] = w4.x;
        Ws[lw_k + 1][lw_o] = w4.y;
        Ws[lw_k + 2][lw_o] = w4.z;
        Ws[lw_k + 3][lw_o] = w4.w;
        const float4 x4 = *(const float4*)(Xbase + (size_t)(c0 + lx_k) * NDIM + n0 + lx_n);
        *(float4*)&Xs[lx_k][lx_n] = x4;
        __syncthreads();

        #pragma unroll
        for (int kk = 0; kk < 16; ++kk) {
            const float4 a = *(const float4*)&Ws[kk][ty << 2];
            const float4 b = *(const float4*)&Xs[kk][tx << 2];
            const float av[4] = {a.x, a.y, a.z, a.w};
            const float bv[4] = {b.x, b.y, b.z, b.w};
            #pragma unroll
            for (int i = 0; i < 4; ++i)
                #pragma unroll
                for (int j = 0; j < 4; ++j)
                    acc[i][j] += av[i] * bv[j];
        }
        __syncthreads();
    }

    // epilogue: BN + LIF, coalesced float4 stores
    #pragma unroll
    for (int i = 0; i < 4; ++i) {
        const int ch = o0 + (ty << 2) + i;
        const float inv  = gamma[ch] / sqrtf(var[ch] + 1e-5f);
        const float bias = beta[ch] - mean[ch] * inv;
        float4 s;
        s.x = (acc[i][0] * inv + bias >= 2.0f) ? 1.0f : 0.0f;
        s.y = (acc[i][1] * inv + bias >= 2.0f) ? 1.0f : 0.0f;
        s.z = (acc[i][2] * inv + bias >= 2.0f) ? 1.0f : 0.0f;
        s.w = (acc[i][3] * inv + bias >= 2.0f) ? 1.0f : 0.0f;
        *(float4*)(out + ((size_t)tb * CDIM + ch) * NDIM + n0 + (tx << 2)) = s;
    }
}

// ---------------------------------------------------------------------------
// Spiking attention via associativity: (QK^T)V == Q(K^T V).
// All intermediates are exact small integers in fp32, so this is bit-exact
// vs the reference order.
//   G[d1][d2] = sum_m K_h[d1][m] * V_h[d2][m]        (<= 512, exact)
//   o'[d][n]  = sum_d1 Q_h[d1][n] * G[d1][d]         (<= 16384, exact)
//   spike     = (o' * 0.25 / 2 >= 1)  <=>  (o' >= 8)  (exact integer compare)
// One block per (tb, h). Layout: Q/K/V spikes stored as (tb, c=h*32+d, n).
// ---------------------------------------------------------------------------
__global__ __launch_bounds__(256) void attn_kernel(
    const float* __restrict__ Qs, const float* __restrict__ Ks,
    const float* __restrict__ Vs, float* __restrict__ S2)
{
    const int tb = blockIdx.x >> 4;
    const int h  = blockIdx.x & 15;
    const int t  = threadIdx.x;

    __shared__ float Ksh[32][65];   // pad 65: conflict-free column reads
    __shared__ float Vsh[32][65];
    __shared__ float Gs[32][33];
    __shared__ float Qsh[32][128];

    const size_t base = ((size_t)tb * CDIM + h * DDIM) * NDIM;
    const float* Kh = Ks + base;
    const float* Vh = Vs + base;
    const float* Qh = Qs + base;

    // ---- phase 1: G = K_h * V_h^T (32x32), register-accumulated ----
    const int d2  = t & 31;   // this thread's G column
    const int d1b = t >> 5;   // 0..7 ; rows d1b + 8*j, j=0..3
    float g[4] = {0.0f, 0.0f, 0.0f, 0.0f};

    const int ld_row = t >> 3;         // 0..31
    const int ld_mm  = (t & 7) << 3;   // 0,8,...,56

    for (int m0 = 0; m0 < NDIM; m0 += 64) {
        {
            const float4 ka = *(const float4*)(Kh + (size_t)ld_row * NDIM + m0 + ld_mm);
            const float4 kb = *(const float4*)(Kh + (size_t)ld_row * NDIM + m0 + ld_mm + 4);
            Ksh[ld_row][ld_mm + 0] = ka.x; Ksh[ld_row][ld_mm + 1] = ka.y;
            Ksh[ld_row][ld_mm + 2] = ka.z; Ksh[ld_row][ld_mm + 3] = ka.w;
            Ksh[ld_row][ld_mm + 4] = kb.x; Ksh[ld_row][ld_mm + 5] = kb.y;
            Ksh[ld_row][ld_mm + 6] = kb.z; Ksh[ld_row][ld_mm + 7] = kb.w;
            const float4 va = *(const float4*)(Vh + (size_t)ld_row * NDIM + m0 + ld_mm);
            const float4 vb = *(const float4*)(Vh + (size_t)ld_row * NDIM + m0 + ld_mm + 4);
            Vsh[ld_row][ld_mm + 0] = va.x; Vsh[ld_row][ld_mm + 1] = va.y;
            Vsh[ld_row][ld_mm + 2] = va.z; Vsh[ld_row][ld_mm + 3] = va.w;
            Vsh[ld_row][ld_mm + 4] = vb.x; Vsh[ld_row][ld_mm + 5] = vb.y;
            Vsh[ld_row][ld_mm + 6] = vb.z; Vsh[ld_row][ld_mm + 7] = vb.w;
        }
        __syncthreads();
        for (int mm = 0; mm < 64; ++mm) {
            const float vv = Vsh[d2][mm];
            #pragma unroll
            for (int j = 0; j < 4; ++j)
                g[j] += Ksh[d1b + 8 * j][mm] * vv;
        }
        __syncthreads();
    }
    #pragma unroll
    for (int j = 0; j < 4; ++j)
        Gs[d1b + 8 * j][d2] = g[j];
    __syncthreads();

    // ---- phase 2: o' = Q_h^T * G, threshold at 8 ----
    const int q_row = t >> 3;          // 0..31
    const int q_col = (t & 7) << 4;    // 0,16,...,112
    for (int n0 = 0; n0 < NDIM; n0 += 128) {
        #pragma unroll
        for (int u = 0; u < 4; ++u) {
            *(float4*)&Qsh[q_row][q_col + 4 * u] =
                *(const float4*)(Qh + (size_t)q_row * NDIM + n0 + q_col + 4 * u);
        }
        __syncthreads();
        #pragma unroll 4
        for (int it = 0; it < 16; ++it) {
            const int idx = t + (it << 8);      // 0..4095
            const int dd  = idx >> 7;           // 0..31
            const int nn  = idx & 127;
            float o = 0.0f;
            #pragma unroll
            for (int dp = 0; dp < 32; ++dp)
                o += Qsh[dp][nn] * Gs[dp][dd];
            S2[base + (size_t)dd * NDIM + n0 + nn] = (o >= 8.0f) ? 1.0f : 0.0f;
        }
        __syncthreads();
    }
}

// ---------------------------------------------------------------------------
extern "C" void kernel_launch(void* const* d_in, const int* in_sizes, int n_in,
                              void* d_out, int out_size, void* d_ws, size_t ws_size,
                              hipStream_t stream)
{
    const float* x   = (const float*)d_in[0];
    const float* y   = (const float*)d_in[1];
    const float* q_w = (const float*)d_in[2];
    const float* q_g = (const float*)d_in[3];
    const float* q_b = (const float*)d_in[4];
    const float* q_m = (const float*)d_in[5];
    const float* q_v = (const float*)d_in[6];
    const float* k_w = (const float*)d_in[7];
    const float* k_g = (const float*)d_in[8];
    const float* k_b = (const float*)d_in[9];
    const float* k_m = (const float*)d_in[10];
    const float* k_v = (const float*)d_in[11];
    const float* v_w = (const float*)d_in[12];
    const float* v_g = (const float*)d_in[13];
    const float* v_b = (const float*)d_in[14];
    const float* v_m = (const float*)d_in[15];
    const float* v_v = (const float*)d_in[16];
    const float* p_w = (const float*)d_in[17];
    const float* p_g = (const float*)d_in[18];
    const float* p_b = (const float*)d_in[19];
    const float* p_m = (const float*)d_in[20];
    const float* p_v = (const float*)d_in[21];

    const size_t PLANE = (size_t)TBDIM * CDIM * NDIM;   // 2,097,152 floats
    float* ws = (float*)d_ws;
    float* Qs = ws;
    float* Ks = ws + PLANE;
    float* Vs = ws + 2 * PLANE;
    float* S2 = ws + 3 * PLANE;

    dim3 grid(NDIM / 64, CDIM / 64, TBDIM);   // 8 x 8 x 8 = 512 blocks
    dim3 block(256);

    gemm_bn_lif<<<grid, block, 0, stream>>>(x, q_w, q_g, q_b, q_m, q_v, Qs);
    gemm_bn_lif<<<grid, block, 0, stream>>>(y, k_w, k_g, k_b, k_m, k_v, Ks);
    gemm_bn_lif<<<grid, block, 0, stream>>>(y, v_w, v_g, v_b, v_m, v_v, Vs);

    attn_kernel<<<dim3(TBDIM * HDIM), block, 0, stream>>>(Qs, Ks, Vs, S2);

    gemm_bn_lif<<<grid, block, 0, stream>>>(S2, p_w, p_g, p_b, p_m, p_v, (float*)d_out);
}

// Round 2
// 250.830 us; speedup vs baseline: 1.1377x; 1.1377x over previous
//
#include <hip/hip_runtime.h>
#include <math.h>

// Problem constants (T=4, B=2 -> TB=8)
#define TBDIM 8
#define CDIM  512
#define NDIM  512

typedef unsigned int u32;

// async global->LDS, 16B per lane. LDS dest must be wave-uniform-base + lane*16.
__device__ __forceinline__ void async_ld16(const float* g, float* l) {
    __builtin_amdgcn_global_load_lds(
        (const __attribute__((address_space(1))) u32*)(const u32*)g,
        (__attribute__((address_space(3))) u32*)(u32*)l, 16, 0, 0);
}

// ---------------------------------------------------------------------------
// GEMM + BN + LIF, v2:
//   out[tb][o][n] = ((sum_c W[o][c] X[tb][c][n]) * inv[o] + bias[o] >= 2) ? 1 : 0
// 64x64 tile / 256 threads / 4x4 microtile, BK=32, double-buffered LDS,
// X tile via global_load_lds (contiguous lane layout), W tile via regs->LDS
// with pad-68 rows + interleaved c-mapping (<=2-way writes = free).
// ---------------------------------------------------------------------------
__global__ __launch_bounds__(256) void gemm_bn_lif(
    const float* __restrict__ X, const float* __restrict__ W,
    const float* __restrict__ gamma, const float* __restrict__ beta,
    const float* __restrict__ mean, const float* __restrict__ var,
    float* __restrict__ out)
{
    const int tb = blockIdx.z;
    const int n0 = blockIdx.x * 64;
    const int o0 = blockIdx.y * 64;
    const int t  = threadIdx.x;

    __shared__ __align__(16) float Xs[2][32 * 64];   // [c][n], unpadded (DMA layout)
    __shared__ __align__(16) float Ws[2][32][68];    // [c][o], pad 68 (16B-aligned rows)

    const int ty = t >> 4;     // o microtile row 0..15
    const int tx = t & 15;     // n microtile col 0..15

    // W staging map: lane -> (o = t>>2, c = (t&3)*4 + {0..3} + 16p)
    const int wo = t >> 2;
    const int wc = (t & 3) << 2;

    const float* Xb = X + (size_t)tb * CDIM * NDIM;
    const float* Wb = W + (size_t)(o0 + wo) * CDIM + wc;

    float acc[4][4];
    #pragma unroll
    for (int i = 0; i < 4; ++i)
        #pragma unroll
        for (int j = 0; j < 4; ++j) acc[i][j] = 0.0f;

    // ---- prologue: stage chunk 0 into buf 0 ----
    {
        #pragma unroll
        for (int p = 0; p < 2; ++p) {
            const int flat = (p << 10) + (t << 2);
            const int row  = flat >> 6;
            const int col  = flat & 63;
            async_ld16(Xb + (size_t)row * NDIM + n0 + col, &Xs[0][flat]);
        }
        const float4 w0 = *(const float4*)(Wb);
        const float4 w1 = *(const float4*)(Wb + 16);
        Ws[0][wc + 0][wo] = w0.x; Ws[0][wc + 1][wo] = w0.y;
        Ws[0][wc + 2][wo] = w0.z; Ws[0][wc + 3][wo] = w0.w;
        Ws[0][wc + 16][wo] = w1.x; Ws[0][wc + 17][wo] = w1.y;
        Ws[0][wc + 18][wo] = w1.z; Ws[0][wc + 19][wo] = w1.w;
    }

    for (int i = 0; i < 16; ++i) {
        const int buf = i & 1;
        const bool more = (i < 15);
        float4 w0n, w1n;
        if (more) {
            const int c0n = (i + 1) << 5;
            w0n = *(const float4*)(Wb + c0n);
            w1n = *(const float4*)(Wb + c0n + 16);
        }
        __syncthreads();   // chunk i's loads (issued last iter) are now complete
        if (more) {
            const int c0n = (i + 1) << 5;
            const int nb  = buf ^ 1;
            #pragma unroll
            for (int p = 0; p < 2; ++p) {
                const int flat = (p << 10) + (t << 2);
                const int row  = flat >> 6;
                const int col  = flat & 63;
                async_ld16(Xb + (size_t)(c0n + row) * NDIM + n0 + col, &Xs[nb][flat]);
            }
            Ws[nb][wc + 0][wo] = w0n.x; Ws[nb][wc + 1][wo] = w0n.y;
            Ws[nb][wc + 2][wo] = w0n.z; Ws[nb][wc + 3][wo] = w0n.w;
            Ws[nb][wc + 16][wo] = w1n.x; Ws[nb][wc + 17][wo] = w1n.y;
            Ws[nb][wc + 18][wo] = w1n.z; Ws[nb][wc + 19][wo] = w1n.w;
        }
        // compute on buf
        #pragma unroll 8
        for (int kk = 0; kk < 32; ++kk) {
            const float4 a = *(const float4*)&Ws[buf][kk][ty << 2];
            const float4 b = *(const float4*)&Xs[buf][(kk << 6) | (tx << 2)];
            acc[0][0] += a.x * b.x; acc[0][1] += a.x * b.y; acc[0][2] += a.x * b.z; acc[0][3] += a.x * b.w;
            acc[1][0] += a.y * b.x; acc[1][1] += a.y * b.y; acc[1][2] += a.y * b.z; acc[1][3] += a.y * b.w;
            acc[2][0] += a.z * b.x; acc[2][1] += a.z * b.y; acc[2][2] += a.z * b.z; acc[2][3] += a.z * b.w;
            acc[3][0] += a.w * b.x; acc[3][1] += a.w * b.y; acc[3][2] += a.w * b.z; acc[3][3] += a.w * b.w;
        }
    }

    // epilogue: BN + LIF, coalesced float4 stores
    #pragma unroll
    for (int i = 0; i < 4; ++i) {
        const int ch = o0 + (ty << 2) + i;
        const float inv  = gamma[ch] / sqrtf(var[ch] + 1e-5f);
        const float bias = beta[ch] - mean[ch] * inv;
        float4 s;
        s.x = (acc[i][0] * inv + bias >= 2.0f) ? 1.0f : 0.0f;
        s.y = (acc[i][1] * inv + bias >= 2.0f) ? 1.0f : 0.0f;
        s.z = (acc[i][2] * inv + bias >= 2.0f) ? 1.0f : 0.0f;
        s.w = (acc[i][3] * inv + bias >= 2.0f) ? 1.0f : 0.0f;
        *(float4*)(out + ((size_t)tb * CDIM + ch) * NDIM + n0 + (tx << 2)) = s;
    }
}

// ---------------------------------------------------------------------------
// attn_g: partial Gram matrix G[d1][d2] = sum_{m in half} K_h[d1][m] V_h[d2][m]
// Exact small integers. One block per (tbh, m-half). 2x2 microtile/thread.
// Gw layout: [blockIdx.x][d1*32 + d2]  (1 MB total, lives in d_out scratch)
// ---------------------------------------------------------------------------
__global__ __launch_bounds__(256) void attn_g(
    const float* __restrict__ Ks, const float* __restrict__ Vs,
    float* __restrict__ Gw)
{
    const int tbh  = blockIdx.x >> 1;   // 0..127 = tb*16 + h
    const int m0   = (blockIdx.x & 1) << 8;
    const int t    = threadIdx.x;

    __shared__ __align__(16) float Ksh[32 * 260];   // pad 260: rows 16B-aligned
    __shared__ __align__(16) float Vsh[32 * 260];

    const float* Kh = Ks + (size_t)tbh * 32 * NDIM;
    const float* Vh = Vs + (size_t)tbh * 32 * NDIM;

    #pragma unroll
    for (int i = 0; i < 8; ++i) {
        const int flat = (i << 10) + (t << 2);
        const int row  = flat >> 8;       // 0..31
        const int col  = flat & 255;
        *(float4*)&Ksh[row * 260 + col] = *(const float4*)(Kh + (size_t)row * NDIM + m0 + col);
        *(float4*)&Vsh[row * 260 + col] = *(const float4*)(Vh + (size_t)row * NDIM + m0 + col);
    }
    __syncthreads();

    const int d1a = t >> 4;   // 0..15 ; rows d1a, d1a+16
    const int d2a = t & 15;   // 0..15 ; cols d2a, d2a+16
    float a00 = 0.f, a01 = 0.f, a10 = 0.f, a11 = 0.f;

    #pragma unroll 8
    for (int m = 0; m < 256; m += 4) {
        const float4 k0 = *(const float4*)&Ksh[d1a * 260 + m];
        const float4 k1 = *(const float4*)&Ksh[(d1a + 16) * 260 + m];
        const float4 v0 = *(const float4*)&Vsh[d2a * 260 + m];
        const float4 v1 = *(const float4*)&Vsh[(d2a + 16) * 260 + m];
        a00 += k0.x * v0.x + k0.y * v0.y + k0.z * v0.z + k0.w * v0.w;
        a01 += k0.x * v1.x + k0.y * v1.y + k0.z * v1.z + k0.w * v1.w;
        a10 += k1.x * v0.x + k1.y * v0.y + k1.z * v0.z + k1.w * v0.w;
        a11 += k1.x * v1.x + k1.y * v1.y + k1.z * v1.z + k1.w * v1.w;
    }

    float* gout = Gw + (size_t)blockIdx.x * 1024;
    gout[d1a * 32 + d2a]             = a00;
    gout[d1a * 32 + d2a + 16]        = a01;
    gout[(d1a + 16) * 32 + d2a]      = a10;
    gout[(d1a + 16) * 32 + d2a + 16] = a11;
}

// ---------------------------------------------------------------------------
// attn_s: o'[d][n] = sum_dp Q_h[dp][n] * G[dp][d];  spike = (o' >= 8)
// 512 blocks = (tbh, n-chunk of 128). G (summed halves) in LDS; Q streamed
// directly from global (each element used exactly once) as coalesced float4.
// ---------------------------------------------------------------------------
__global__ __launch_bounds__(256) void attn_s(
    const float* __restrict__ Qs, const float* __restrict__ Gw,
    float* __restrict__ S2)
{
    const int bx  = blockIdx.x;
    const int tbh = bx >> 2;
    const int n0  = (bx & 3) << 7;
    const int t   = threadIdx.x;

    __shared__ __align__(16) float Gsh[32 * 36];   // [dp][dd], pad 36

    const float* g0 = Gw + (size_t)tbh * 2048;
    {
        const int idx = t << 2;            // 0..1023, step 4
        const float4 ga = *(const float4*)(g0 + idx);
        const float4 gb = *(const float4*)(g0 + 1024 + idx);
        const int dp = idx >> 5;
        const int dd = idx & 31;
        float4 gs;
        gs.x = ga.x + gb.x; gs.y = ga.y + gb.y; gs.z = ga.z + gb.z; gs.w = ga.w + gb.w;
        *(float4*)&Gsh[dp * 36 + dd] = gs;
    }
    __syncthreads();

    const float* Qh = Qs + (size_t)tbh * 32 * NDIM;
    const int r  = t >> 5;            // 0..7 ; dd = r + 8j
    const int nn = (t & 31) << 2;     // 0..124

    float o[4][4];
    #pragma unroll
    for (int j = 0; j < 4; ++j)
        #pragma unroll
        for (int u = 0; u < 4; ++u) o[j][u] = 0.0f;

    #pragma unroll 8
    for (int dp = 0; dp < 32; ++dp) {
        const float4 q = *(const float4*)(Qh + (size_t)dp * NDIM + n0 + nn);
        #pragma unroll
        for (int j = 0; j < 4; ++j) {
            const float gv = Gsh[dp * 36 + r + 8 * j];
            o[j][0] += q.x * gv; o[j][1] += q.y * gv;
            o[j][2] += q.z * gv; o[j][3] += q.w * gv;
        }
    }

    float* Sh = S2 + (size_t)tbh * 32 * NDIM;
    #pragma unroll
    for (int j = 0; j < 4; ++j) {
        float4 s;
        s.x = (o[j][0] >= 8.0f) ? 1.0f : 0.0f;
        s.y = (o[j][1] >= 8.0f) ? 1.0f : 0.0f;
        s.z = (o[j][2] >= 8.0f) ? 1.0f : 0.0f;
        s.w = (o[j][3] >= 8.0f) ? 1.0f : 0.0f;
        *(float4*)(Sh + (size_t)(r + 8 * j) * NDIM + n0 + nn) = s;
    }
}

// ---------------------------------------------------------------------------
extern "C" void kernel_launch(void* const* d_in, const int* in_sizes, int n_in,
                              void* d_out, int out_size, void* d_ws, size_t ws_size,
                              hipStream_t stream)
{
    const float* x   = (const float*)d_in[0];
    const float* y   = (const float*)d_in[1];
    const float* q_w = (const float*)d_in[2];
    const float* q_g = (const float*)d_in[3];
    const float* q_b = (const float*)d_in[4];
    const float* q_m = (const float*)d_in[5];
    const float* q_v = (const float*)d_in[6];
    const float* k_w = (const float*)d_in[7];
    const float* k_g = (const float*)d_in[8];
    const float* k_b = (const float*)d_in[9];
    const float* k_m = (const float*)d_in[10];
    const float* k_v = (const float*)d_in[11];
    const float* v_w = (const float*)d_in[12];
    const float* v_g = (const float*)d_in[13];
    const float* v_b = (const float*)d_in[14];
    const float* v_m = (const float*)d_in[15];
    const float* v_v = (const float*)d_in[16];
    const float* p_w = (const float*)d_in[17];
    const float* p_g = (const float*)d_in[18];
    const float* p_b = (const float*)d_in[19];
    const float* p_m = (const float*)d_in[20];
    const float* p_v = (const float*)d_in[21];

    const size_t PLANE = (size_t)TBDIM * CDIM * NDIM;   // 2,097,152 floats
    float* ws = (float*)d_ws;
    float* Qs = ws;
    float* Ks = ws + PLANE;
    float* Vs = ws + 2 * PLANE;
    float* S2 = ws + 3 * PLANE;
    // Gram-matrix scratch lives in d_out: it is consumed by attn_s before the
    // final gemm overwrites d_out. 256 blocks * 1024 floats = 1 MB << 8 MB.
    float* Gw = (float*)d_out;

    dim3 grid(NDIM / 64, CDIM / 64, TBDIM);   // 8 x 8 x 8 = 512 blocks
    dim3 block(256);

    gemm_bn_lif<<<grid, block, 0, stream>>>(x, q_w, q_g, q_b, q_m, q_v, Qs);
    gemm_bn_lif<<<grid, block, 0, stream>>>(y, k_w, k_g, k_b, k_m, k_v, Ks);
    gemm_bn_lif<<<grid, block, 0, stream>>>(y, v_w, v_g, v_b, v_m, v_v, Vs);

    attn_g<<<dim3(TBDIM * 16 * 2), block, 0, stream>>>(Ks, Vs, Gw);
    attn_s<<<dim3(TBDIM * 16 * 4), block, 0, stream>>>(Qs, Gw, S2);

    gemm_bn_lif<<<grid, block, 0, stream>>>(S2, p_w, p_g, p_b, p_m, p_v, (float*)d_out);
}

// Round 3
// 186.783 us; speedup vs baseline: 1.5278x; 1.3429x over previous
//
#include <hip/hip_runtime.h>
#include <math.h>

#define TBD 8
#define CD  512
#define ND  512
#define PLANE (TBD*CD*ND)   // 2,097,152 elems per bf16 spike/activation plane
#define WPL   (CD*CD)       // 262,144 elems per bf16 weight plane

typedef __attribute__((ext_vector_type(8))) short bf16x8;
typedef __attribute__((ext_vector_type(4))) float f32x4;

__device__ __forceinline__ float b2f(unsigned short u){
  union{unsigned int i; float f;} x; x.i = ((unsigned int)u) << 16; return x.f;
}
// fp32 -> bf16 round-to-nearest-even
__device__ __forceinline__ unsigned short f2b(float f){
  unsigned int u = __builtin_bit_cast(unsigned int, f);
  u += 0x7fffu + ((u >> 16) & 1u);
  return (unsigned short)(u >> 16);
}
__device__ __forceinline__ void async_ld16(const unsigned short* g, unsigned short* l){
  __builtin_amdgcn_global_load_lds((const __attribute__((address_space(1))) unsigned int*)g,
      (__attribute__((address_space(3))) unsigned int*)l, 16, 0, 0);
}

// ---------------------------------------------------------------------------
// prep:
//  blocks [0,1024):   x/y -> 3 bf16 planes each, TRANSPOSED to [tb][n][c]
//                     (exact 3-way split: w1+w2+w3 == fp32 value exactly)
//  blocks [1024,2048): 4 weight matrices -> 3 bf16 planes each, [o][c]
//  blocks [2048,2056): BN inv/bias precompute (bitwise same formula as ref)
// ---------------------------------------------------------------------------
__global__ __launch_bounds__(256) void prep(
    const float* __restrict__ x, const float* __restrict__ y,
    const float* __restrict__ Qw, const float* __restrict__ Kw,
    const float* __restrict__ Vw, const float* __restrict__ Pw,
    const float* __restrict__ Qg, const float* __restrict__ Qb, const float* __restrict__ Qm, const float* __restrict__ Qv,
    const float* __restrict__ Kg, const float* __restrict__ Kb, const float* __restrict__ Km, const float* __restrict__ Kv,
    const float* __restrict__ Vg, const float* __restrict__ Vb, const float* __restrict__ Vm, const float* __restrict__ Vv,
    const float* __restrict__ Pg, const float* __restrict__ Pb, const float* __restrict__ Pm, const float* __restrict__ Pv,
    unsigned short* __restrict__ wsu, float* __restrict__ ib)
{
  const int bx = blockIdx.x, t = threadIdx.x;
  if (bx < 1024) {
    __shared__ __align__(16) float tl[64][68];
    const int inp = bx >> 9, rem = bx & 511;
    const int tb = rem >> 6, tile = rem & 63;
    const int ct = (tile & 7) << 6, nt = (tile >> 3) << 6;
    const float* xg = inp ? y : x;
    #pragma unroll
    for (int r = 0; r < 4; ++r) {
      const int row = (t >> 4) + (r << 4);
      const int col = (t & 15) << 2;
      *(float4*)&tl[row][col] =
          *(const float4*)(xg + ((size_t)(tb*CD + ct + row))*ND + nt + col);
    }
    __syncthreads();
    const int nl = t >> 2, cb = (t & 3) << 4;
    __align__(16) unsigned short h[3][16];
    #pragma unroll
    for (int j = 0; j < 16; ++j) {
      const float f = tl[cb + j][nl];
      const unsigned short a = f2b(f);  const float r1 = f - b2f(a);
      const unsigned short b = f2b(r1); const float r2 = r1 - b2f(b);
      h[0][j] = a; h[1][j] = b; h[2][j] = f2b(r2);
    }
    unsigned short* base = wsu + (size_t)inp*3*PLANE;
    const size_t rowo = ((size_t)tb*ND + nt + nl)*CD + ct + cb;
    #pragma unroll
    for (int s = 0; s < 3; ++s) {
      *(uint4*)(base + (size_t)s*PLANE + rowo)     = *(uint4*)&h[s][0];
      *(uint4*)(base + (size_t)s*PLANE + rowo + 8) = *(uint4*)&h[s][8];
    }
  } else if (bx < 2048) {
    const int b2 = bx - 1024;
    const int mat = b2 >> 8, rr = b2 & 255;
    const float* Wg = (mat==0)?Qw:(mat==1)?Kw:(mat==2)?Vw:Pw;
    const int row = (rr << 1) + (t >> 7);
    const int col = (t & 127) << 2;
    const float4 w = *(const float4*)(Wg + (size_t)row*CD + col);
    const float f[4] = {w.x, w.y, w.z, w.w};
    __align__(8) unsigned short h[3][4];
    #pragma unroll
    for (int j = 0; j < 4; ++j) {
      const unsigned short a = f2b(f[j]);  const float r1 = f[j] - b2f(a);
      const unsigned short b = f2b(r1);    const float r2 = r1 - b2f(b);
      h[0][j] = a; h[1][j] = b; h[2][j] = f2b(r2);
    }
    unsigned short* base = wsu + (size_t)6*PLANE + (size_t)mat*3*WPL;
    #pragma unroll
    for (int s = 0; s < 3; ++s)
      *(uint2*)(base + (size_t)s*WPL + (size_t)row*CD + col) = *(uint2*)&h[s][0];
  } else {
    const int idx = (bx - 2048)*256 + t;   // 0..2047
    const int br = idx >> 9, ch = idx & 511;
    const float* G = (br==0)?Qg:(br==1)?Kg:(br==2)?Vg:Pg;
    const float* B = (br==0)?Qb:(br==1)?Kb:(br==2)?Vb:Pb;
    const float* M = (br==0)?Qm:(br==1)?Km:(br==2)?Vm:Pm;
    const float* V = (br==0)?Qv:(br==1)?Kv:(br==2)?Vv:Pv;
    const float inv = G[ch] / sqrtf(V[ch] + 1e-5f);
    ib[br*1024 + ch]       = inv;
    ib[br*1024 + 512 + ch] = B[ch] - M[ch]*inv;
  }
}

// ---------------------------------------------------------------------------
// Split-bf16 MFMA GEMM + BN + LIF.
//  A: 3 exact bf16 W-planes [o][c] (stride WPL). B: XS bf16 planes [tb*N+n][c]
//  (stride PLANE). XS=3: activation splits (6 products, i+j<=4).
//  XS=1: binary spikes (3 products, exact).
// 64x64 tile, 256 thr, wave-tile 32x32 (2x2 of 16x16x32 MFMA), BK=32,
// double-buffered, global_load_lds(16B) staging, XOR-swizzled LDS k-blocks
// for conflict-free ds_read_b128 fragments.
// ---------------------------------------------------------------------------
template<int XS, bool F32OUT>
__global__ __launch_bounds__(256) void gemm_mfma(
    const unsigned short* __restrict__ Ab,
    const unsigned short* __restrict__ Bbp,
    const float* __restrict__ ibp,
    unsigned short* __restrict__ outb,
    float* __restrict__ outf)
{
  const int bx  = blockIdx.x;
  const int idx = bx & 511;
  const int br  = bx >> 9;                 // 0..2 for qkv launch, 0 for final
  const int tb  = idx & 7;                 // consecutive blocks -> XCD = tb
  const int o0  = ((idx >> 3) & 7) << 6;
  const int n0  = (idx >> 6) << 6;
  const int t    = threadIdx.x;
  const int lane = t & 63, wave = t >> 6;

  const unsigned short* A = Ab + (size_t)br*3*WPL;
  const unsigned short* B = Bbp + (size_t)(br ? 3 : 0)*PLANE;
  const float* IB = ibp + br*1024;

  __shared__ __align__(16) unsigned short Al[2][3][4][512];
  __shared__ __align__(16) unsigned short Bl[2][XS][4][512];

  // DMA lane mapping: slot lane -> row=lane>>2, swizzled k-block
  const int lr = lane >> 2;
  const int lc = (((lane & 3) ^ ((lane >> 3) & 3)) << 3);
  constexpr int TPW = (12 + 4*XS) / 4;     // tiles per wave

  auto stage = [&](int buf, int c0) {
    #pragma unroll
    for (int j = 0; j < TPW; ++j) {
      const int tix = wave*TPW + j;
      if (tix < 12) {
        const int s = tix >> 2, ot = tix & 3;
        const unsigned short* g = A + (size_t)s*WPL
            + (size_t)(o0 + (ot << 4) + lr)*CD + c0 + lc;
        async_ld16(g, &Al[buf][s][ot][lane << 3]);
      } else {
        const int k = tix - 12, s = k >> 2, nt = k & 3;
        const unsigned short* g = B + (size_t)s*PLANE
            + ((size_t)tb*ND + n0 + (nt << 4) + lr)*CD + c0 + lc;
        async_ld16(g, &Bl[buf][s][nt][lane << 3]);
      }
    }
  };

  f32x4 acc[2][2];
  const f32x4 zero = {0.f, 0.f, 0.f, 0.f};
  acc[0][0] = zero; acc[0][1] = zero; acc[1][0] = zero; acc[1][1] = zero;

  const int otb = (wave >> 1) << 1;        // wave's base 16-tile in o
  const int ntb = (wave & 1) << 1;         // wave's base 16-tile in n
  // fragment offset: m=lane&15 rows of 32, swizzled k-block (lane>>4)
  const int fo = ((lane & 15) << 5) + ((((lane >> 4) ^ ((lane >> 1) & 3)) & 3) << 3);

  stage(0, 0);
  for (int i = 0; i < 16; ++i) {
    const int buf = i & 1;
    __syncthreads();                        // drains DMA for chunk i
    if (i < 15) stage(buf ^ 1, (i + 1) << 5);

    bf16x8 Af[3][2], Bf[XS][2];
    #pragma unroll
    for (int s = 0; s < 3; ++s)
      #pragma unroll
      for (int oy = 0; oy < 2; ++oy)
        Af[s][oy] = *(const bf16x8*)&Al[buf][s][otb + oy][fo];
    #pragma unroll
    for (int s = 0; s < XS; ++s)
      #pragma unroll
      for (int nx = 0; nx < 2; ++nx)
        Bf[s][nx] = *(const bf16x8*)&Bl[buf][s][ntb + nx][fo];

    auto mm = [&](int sa, int sb) {
      #pragma unroll
      for (int oy = 0; oy < 2; ++oy)
        #pragma unroll
        for (int nx = 0; nx < 2; ++nx)
          acc[oy][nx] = __builtin_amdgcn_mfma_f32_16x16x32_bf16(
              Af[sa][oy], Bf[sb][nx], acc[oy][nx], 0, 0, 0);
    };
    if constexpr (XS == 3) {
      mm(0,0); mm(0,1); mm(1,0); mm(1,1); mm(0,2); mm(2,0);
    } else {
      mm(0,0); mm(1,0); mm(2,0);
    }
  }

  // epilogue: BN + LIF.  C layout (m89): col=lane&15, row=(lane>>4)*4+reg
  const int rbase = (lane >> 4) << 2;
  const int cl = lane & 15;
  #pragma unroll
  for (int oy = 0; oy < 2; ++oy) {
    #pragma unroll
    for (int r = 0; r < 4; ++r) {
      const int ch = o0 + ((otb + oy) << 4) + rbase + r;
      const float inv  = IB[ch];
      const float bias = IB[512 + ch];
      #pragma unroll
      for (int nx = 0; nx < 2; ++nx) {
        const float v = acc[oy][nx][r];
        const bool sp = (v * inv + bias >= 2.0f);
        const int n = n0 + ((ntb + nx) << 4) + cl;
        const size_t off = ((size_t)tb*CD + ch)*ND + n;
        if constexpr (F32OUT) outf[off] = sp ? 1.0f : 0.0f;
        else (outb + (size_t)br*PLANE)[off] = sp ? (unsigned short)0x3F80 : (unsigned short)0;
      }
    }
  }
}

// ---------------------------------------------------------------------------
// Fused attention: per (tb,h,n-chunk) block computes the FULL exact integer
// Gram G = K V^T (32x32), then o' = Q^T G for its 128-n slice; spike = o'>=8.
// Inputs: bf16 spikes [tb][c][n]; output: bf16 spikes TRANSPOSED [tb][n][c].
// ---------------------------------------------------------------------------
__global__ __launch_bounds__(256) void attn(
    const unsigned short* __restrict__ Qs, const unsigned short* __restrict__ Ks,
    const unsigned short* __restrict__ Vs, unsigned short* __restrict__ S2T)
{
  const int tbh = blockIdx.x >> 2;
  const int n0  = (blockIdx.x & 3) << 7;
  const int t   = threadIdx.x;

  __shared__ __align__(16) float sm[2*32*260];   // 66.6 KB, phase-reused
  float* Ksh = sm;
  float* Vsh = sm + 32*260;
  float* Gs  = sm;                                // phase 2 (1056 floats)
  float* Osh = sm + 2048;                         // phase 2 (128*36 floats)

  const unsigned short* Kh = Ks + (size_t)tbh*32*ND;
  const unsigned short* Vh = Vs + (size_t)tbh*32*ND;
  const unsigned short* Qh = Qs + (size_t)tbh*32*ND;

  // ---- phase 1: G = K V^T, exact integers ----
  const int d1a = t >> 4, d2a = t & 15;
  float a00 = 0.f, a01 = 0.f, a10 = 0.f, a11 = 0.f;
  const int srow = t & 31, scb = (t >> 5) << 5;

  for (int m0 = 0; m0 < ND; m0 += 256) {
    if (m0) __syncthreads();
    #pragma unroll
    for (int q = 0; q < 4; ++q) {
      const uint4 kraw = *(const uint4*)(Kh + (size_t)srow*ND + m0 + scb + (q<<3));
      const uint4 vraw = *(const uint4*)(Vh + (size_t)srow*ND + m0 + scb + (q<<3));
      const unsigned short* kr = (const unsigned short*)&kraw;
      const unsigned short* vr = (const unsigned short*)&vraw;
      float4 k0 = {b2f(kr[0]), b2f(kr[1]), b2f(kr[2]), b2f(kr[3])};
      float4 k1 = {b2f(kr[4]), b2f(kr[5]), b2f(kr[6]), b2f(kr[7])};
      float4 v0 = {b2f(vr[0]), b2f(vr[1]), b2f(vr[2]), b2f(vr[3])};
      float4 v1 = {b2f(vr[4]), b2f(vr[5]), b2f(vr[6]), b2f(vr[7])};
      *(float4*)&Ksh[srow*260 + scb + (q<<3)]     = k0;
      *(float4*)&Ksh[srow*260 + scb + (q<<3) + 4] = k1;
      *(float4*)&Vsh[srow*260 + scb + (q<<3)]     = v0;
      *(float4*)&Vsh[srow*260 + scb + (q<<3) + 4] = v1;
    }
    __syncthreads();
    #pragma unroll 8
    for (int m = 0; m < 256; m += 4) {
      const float4 k0 = *(const float4*)&Ksh[d1a*260 + m];
      const float4 k1 = *(const float4*)&Ksh[(d1a+16)*260 + m];
      const float4 v0 = *(const float4*)&Vsh[d2a*260 + m];
      const float4 v1 = *(const float4*)&Vsh[(d2a+16)*260 + m];
      a00 += k0.x*v0.x + k0.y*v0.y + k0.z*v0.z + k0.w*v0.w;
      a01 += k0.x*v1.x + k0.y*v1.y + k0.z*v1.z + k0.w*v1.w;
      a10 += k1.x*v0.x + k1.y*v0.y + k1.z*v0.z + k1.w*v0.w;
      a11 += k1.x*v1.x + k1.y*v1.y + k1.z*v1.z + k1.w*v1.w;
    }
  }
  __syncthreads();
  Gs[d1a*33 + d2a]           = a00;
  Gs[d1a*33 + d2a + 16]      = a01;
  Gs[(d1a+16)*33 + d2a]      = a10;
  Gs[(d1a+16)*33 + d2a + 16] = a11;
  __syncthreads();

  // ---- phase 2: o' = Q^T G (exact <=16384), threshold 8 ----
  const int r  = t >> 5;             // dd = r + 8j
  const int nn = (t & 31) << 2;
  float o[4][4];
  #pragma unroll
  for (int j = 0; j < 4; ++j)
    #pragma unroll
    for (int u = 0; u < 4; ++u) o[j][u] = 0.f;

  #pragma unroll 4
  for (int dp = 0; dp < 32; ++dp) {
    const uint2 qraw = *(const uint2*)(Qh + (size_t)dp*ND + n0 + nn);
    const unsigned short* qr = (const unsigned short*)&qraw;
    const float q0 = b2f(qr[0]), q1 = b2f(qr[1]), q2 = b2f(qr[2]), q3 = b2f(qr[3]);
    #pragma unroll
    for (int j = 0; j < 4; ++j) {
      const float gv = Gs[dp*33 + r + (j<<3)];
      o[j][0] += q0*gv; o[j][1] += q1*gv; o[j][2] += q2*gv; o[j][3] += q3*gv;
    }
  }
  #pragma unroll
  for (int j = 0; j < 4; ++j)
    #pragma unroll
    for (int u = 0; u < 4; ++u)
      Osh[(nn+u)*36 + r + (j<<3)] = o[j][u];
  __syncthreads();

  // transposed bf16 pack-out: S2T[tb][n][c]
  const int n   = t >> 1;
  const int cb2 = (t & 1) << 4;
  __align__(16) unsigned short h[16];
  #pragma unroll
  for (int j = 0; j < 16; j += 4) {
    const float4 f = *(const float4*)&Osh[n*36 + cb2 + j];
    h[j]   = (f.x >= 8.0f) ? 0x3F80 : 0;
    h[j+1] = (f.y >= 8.0f) ? 0x3F80 : 0;
    h[j+2] = (f.z >= 8.0f) ? 0x3F80 : 0;
    h[j+3] = (f.w >= 8.0f) ? 0x3F80 : 0;
  }
  const int tb = tbh >> 4, hh = tbh & 15;
  unsigned short* dst = S2T + ((size_t)tb*ND + n0 + n)*CD + (hh << 5) + cb2;
  *(uint4*)(dst)     = *(uint4*)&h[0];
  *(uint4*)(dst + 8) = *(uint4*)&h[8];
}

// ---------------------------------------------------------------------------
extern "C" void kernel_launch(void* const* d_in, const int* in_sizes, int n_in,
                              void* d_out, int out_size, void* d_ws, size_t ws_size,
                              hipStream_t stream)
{
  const float* x  = (const float*)d_in[0];
  const float* y  = (const float*)d_in[1];
  const float* qw = (const float*)d_in[2];
  const float* qg = (const float*)d_in[3];
  const float* qb = (const float*)d_in[4];
  const float* qm = (const float*)d_in[5];
  const float* qv = (const float*)d_in[6];
  const float* kw = (const float*)d_in[7];
  const float* kg = (const float*)d_in[8];
  const float* kb = (const float*)d_in[9];
  const float* km = (const float*)d_in[10];
  const float* kv = (const float*)d_in[11];
  const float* vw = (const float*)d_in[12];
  const float* vg = (const float*)d_in[13];
  const float* vb = (const float*)d_in[14];
  const float* vm = (const float*)d_in[15];
  const float* vv = (const float*)d_in[16];
  const float* pw = (const float*)d_in[17];
  const float* pg = (const float*)d_in[18];
  const float* pb = (const float*)d_in[19];
  const float* pm = (const float*)d_in[20];
  const float* pv = (const float*)d_in[21];

  unsigned short* wsu = (unsigned short*)d_ws;
  // layout (ushort units): xT[3] | yT[3] | W q/k/v/p [3 each] | Q,K,V spikes | S2T
  unsigned short* Wq  = wsu + (size_t)6*PLANE;
  unsigned short* SPK = wsu + (size_t)6*PLANE + 12*WPL;
  unsigned short* S2T = SPK + (size_t)3*PLANE;
  float* ib = (float*)(wsu + (size_t)10*PLANE + 12*WPL);

  prep<<<2056, 256, 0, stream>>>(x, y, qw, kw, vw, pw,
      qg, qb, qm, qv, kg, kb, km, kv, vg, vb, vm, vv, pg, pb, pm, pv,
      wsu, ib);

  // q/k/v: 3 branches in one launch (br = bx>>9 selects W planes, x vs y, out)
  gemm_mfma<3, false><<<1536, 256, 0, stream>>>(Wq, wsu, ib, SPK, nullptr);

  attn<<<512, 256, 0, stream>>>(SPK, SPK + PLANE, SPK + 2*(size_t)PLANE, S2T);

  // final: binary input (1 plane), 3 exact W splits, fp32 output
  gemm_mfma<1, true><<<512, 256, 0, stream>>>(Wq + (size_t)9*WPL, S2T,
      ib + 3*1024, nullptr, (float*)d_out);
}

// Round 4
// 175.539 us; speedup vs baseline: 1.6257x; 1.0641x over previous
//
#include <hip/hip_runtime.h>
#include <math.h>

#define TBD 8
#define CD  512
#define ND  512
#define PLANE (TBD*CD*ND)   // 2,097,152 elems (u16) per plane
#define WPL   (CD*CD)

typedef unsigned short u16;
typedef unsigned int u32;
typedef _Float16 f16;
typedef __attribute__((ext_vector_type(8))) short bf16x8;
typedef __attribute__((ext_vector_type(8))) _Float16 f16x8;
typedef __attribute__((ext_vector_type(4))) float f32x4;

__device__ __forceinline__ float b2f(u16 u){
  union{u32 i; float f;} x; x.i = ((u32)u) << 16; return x.f;
}
__device__ __forceinline__ u16 f2b(float f){
  u32 u = __builtin_bit_cast(u32, f);
  u += 0x7fffu + ((u >> 16) & 1u);
  return (u16)(u >> 16);
}
__device__ __forceinline__ void async_ld16(const void* g, void* l){
  __builtin_amdgcn_global_load_lds((const __attribute__((address_space(1))) u32*)g,
      (__attribute__((address_space(3))) u32*)l, 16, 0, 0);
}

// ---------------------------------------------------------------------------
// prep (unchanged from r3 — proven):
//  [0,1024):   x/y -> 3 exact bf16 split planes each, transposed to [tb][n][c]
//  [1024,2048): 4 W matrices -> 3 bf16 split planes [o][c]
//  [2048,2056): BN inv/bias
// ---------------------------------------------------------------------------
__global__ __launch_bounds__(256) void prep(
    const float* __restrict__ x, const float* __restrict__ y,
    const float* __restrict__ Qw, const float* __restrict__ Kw,
    const float* __restrict__ Vw, const float* __restrict__ Pw,
    const float* __restrict__ Qg, const float* __restrict__ Qb, const float* __restrict__ Qm, const float* __restrict__ Qv,
    const float* __restrict__ Kg, const float* __restrict__ Kb, const float* __restrict__ Km, const float* __restrict__ Kv,
    const float* __restrict__ Vg, const float* __restrict__ Vb, const float* __restrict__ Vm, const float* __restrict__ Vv,
    const float* __restrict__ Pg, const float* __restrict__ Pb, const float* __restrict__ Pm, const float* __restrict__ Pv,
    u16* __restrict__ wsu, float* __restrict__ ib)
{
  const int bx = blockIdx.x, t = threadIdx.x;
  if (bx < 1024) {
    __shared__ __align__(16) float tl[64][68];
    const int inp = bx >> 9, rem = bx & 511;
    const int tb = rem >> 6, tile = rem & 63;
    const int ct = (tile & 7) << 6, nt = (tile >> 3) << 6;
    const float* xg = inp ? y : x;
    #pragma unroll
    for (int r = 0; r < 4; ++r) {
      const int row = (t >> 4) + (r << 4);
      const int col = (t & 15) << 2;
      *(float4*)&tl[row][col] =
          *(const float4*)(xg + ((size_t)(tb*CD + ct + row))*ND + nt + col);
    }
    __syncthreads();
    const int nl = t >> 2, cb = (t & 3) << 4;
    __align__(16) u16 h[3][16];
    #pragma unroll
    for (int j = 0; j < 16; ++j) {
      const float f = tl[cb + j][nl];
      const u16 a = f2b(f);  const float r1 = f - b2f(a);
      const u16 b = f2b(r1); const float r2 = r1 - b2f(b);
      h[0][j] = a; h[1][j] = b; h[2][j] = f2b(r2);
    }
    u16* base = wsu + (size_t)inp*3*PLANE;
    const size_t rowo = ((size_t)tb*ND + nt + nl)*CD + ct + cb;
    #pragma unroll
    for (int s = 0; s < 3; ++s) {
      *(uint4*)(base + (size_t)s*PLANE + rowo)     = *(uint4*)&h[s][0];
      *(uint4*)(base + (size_t)s*PLANE + rowo + 8) = *(uint4*)&h[s][8];
    }
  } else if (bx < 2048) {
    const int b2 = bx - 1024;
    const int mat = b2 >> 8, rr = b2 & 255;
    const float* Wg = (mat==0)?Qw:(mat==1)?Kw:(mat==2)?Vw:Pw;
    const int row = (rr << 1) + (t >> 7);
    const int col = (t & 127) << 2;
    const float4 w = *(const float4*)(Wg + (size_t)row*CD + col);
    const float f[4] = {w.x, w.y, w.z, w.w};
    __align__(8) u16 h[3][4];
    #pragma unroll
    for (int j = 0; j < 4; ++j) {
      const u16 a = f2b(f[j]);  const float r1 = f[j] - b2f(a);
      const u16 b = f2b(r1);    const float r2 = r1 - b2f(b);
      h[0][j] = a; h[1][j] = b; h[2][j] = f2b(r2);
    }
    u16* base = wsu + (size_t)6*PLANE + (size_t)mat*3*WPL;
    #pragma unroll
    for (int s = 0; s < 3; ++s)
      *(uint2*)(base + (size_t)s*WPL + (size_t)row*CD + col) = *(uint2*)&h[s][0];
  } else {
    const int idx = (bx - 2048)*256 + t;
    const int br = idx >> 9, ch = idx & 511;
    const float* G = (br==0)?Qg:(br==1)?Kg:(br==2)?Vg:Pg;
    const float* B = (br==0)?Qb:(br==1)?Kb:(br==2)?Vb:Pb;
    const float* M = (br==0)?Qm:(br==1)?Km:(br==2)?Vm:Pm;
    const float* V = (br==0)?Qv:(br==1)?Kv:(br==2)?Vv:Pv;
    const float inv = G[ch] / sqrtf(V[ch] + 1e-5f);
    ib[br*1024 + ch]       = inv;
    ib[br*1024 + 512 + ch] = B[ch] - M[ch]*inv;
  }
}

// ---------------------------------------------------------------------------
// Split-bf16 MFMA GEMM + BN + LIF (r3 main loop, new bounce epilogues).
//  XS=3 (qkv fused): br0 -> QT f16 [tb][n][c]; br1/2 -> K/V f16 [tb][c][n].
//  XS=1 (final):     fp32 spikes -> outf [tb][c][n], coalesced float4.
// ---------------------------------------------------------------------------
template<int XS>
__global__ __launch_bounds__(256) void gemm_mfma(
    const u16* __restrict__ Ab, const u16* __restrict__ Bbp,
    const float* __restrict__ ibp,
    u16* __restrict__ qt, u16* __restrict__ spk, float* __restrict__ outf)
{
  const int bx  = blockIdx.x;
  const int idx = bx & 511;
  const int br  = bx >> 9;
  const int tb  = idx & 7;
  const int o0  = ((idx >> 3) & 7) << 6;
  const int n0  = (idx >> 6) << 6;
  const int t    = threadIdx.x;
  const int lane = t & 63, wave = t >> 6;

  const u16* A = Ab + (size_t)br*3*WPL;
  const u16* B = Bbp + (size_t)(br ? 3 : 0)*PLANE;
  const float* IB = ibp + br*1024;

  __shared__ __align__(16) u16 smem[2*3*4*512 + 2*XS*4*512];
  u16* Al = smem;                       // [buf][s][ot][512]
  u16* Bl = smem + 2*3*4*512;           // [buf][s][nt][512]

  const int lr = lane >> 2;
  const int lc = ((lane & 3) ^ ((lane >> 3) & 3)) << 3;
  constexpr int TPW = (12 + 4*XS) / 4;

  auto stage = [&](int buf, int c0) {
    #pragma unroll
    for (int j = 0; j < TPW; ++j) {
      const int tix = wave*TPW + j;
      if (tix < 12) {
        const int s = tix >> 2, ot = tix & 3;
        async_ld16(A + (size_t)s*WPL + (size_t)(o0 + (ot<<4) + lr)*CD + c0 + lc,
                   Al + (((buf*3 + s)*4 + ot) << 9) + (lane << 3));
      } else {
        const int k = tix - 12, s = k >> 2, nt = k & 3;
        async_ld16(B + (size_t)s*PLANE + ((size_t)tb*ND + n0 + (nt<<4) + lr)*CD + c0 + lc,
                   Bl + (((buf*XS + s)*4 + nt) << 9) + (lane << 3));
      }
    }
  };

  f32x4 acc[2][2];
  const f32x4 zero = {0.f, 0.f, 0.f, 0.f};
  acc[0][0] = zero; acc[0][1] = zero; acc[1][0] = zero; acc[1][1] = zero;

  const int otb = (wave >> 1) << 1;
  const int ntb = (wave & 1) << 1;
  const int fo = ((lane & 15) << 5) + ((((lane >> 4) ^ ((lane >> 1) & 3)) & 3) << 3);

  stage(0, 0);
  for (int i = 0; i < 16; ++i) {
    const int buf = i & 1;
    __syncthreads();
    if (i < 15) stage(buf ^ 1, (i + 1) << 5);

    bf16x8 Af[3][2], Bf[XS][2];
    #pragma unroll
    for (int s = 0; s < 3; ++s)
      #pragma unroll
      for (int oy = 0; oy < 2; ++oy)
        Af[s][oy] = *(const bf16x8*)(Al + (((buf*3 + s)*4 + otb + oy) << 9) + fo);
    #pragma unroll
    for (int s = 0; s < XS; ++s)
      #pragma unroll
      for (int nx = 0; nx < 2; ++nx)
        Bf[s][nx] = *(const bf16x8*)(Bl + (((buf*XS + s)*4 + ntb + nx) << 9) + fo);

    auto mm = [&](int sa, int sb) {
      #pragma unroll
      for (int oy = 0; oy < 2; ++oy)
        #pragma unroll
        for (int nx = 0; nx < 2; ++nx)
          acc[oy][nx] = __builtin_amdgcn_mfma_f32_16x16x32_bf16(
              Af[sa][oy], Bf[sb][nx], acc[oy][nx], 0, 0, 0);
    };
    if constexpr (XS == 3) {
      mm(0,0); mm(0,1); mm(1,0); mm(1,1); mm(0,2); mm(2,0);
    } else {
      mm(0,0); mm(1,0); mm(2,0);
    }
  }

  // ---- epilogue: BN + LIF through LDS bounce (reuse staging LDS) ----
  __syncthreads();
  const int rbase = (lane >> 4) << 2;
  const int cl = lane & 15;

  if constexpr (XS == 1) {
    float* Fb = (float*)smem;   // [64][68]
    #pragma unroll
    for (int oy = 0; oy < 2; ++oy)
      #pragma unroll
      for (int r = 0; r < 4; ++r) {
        const int chl = ((otb + oy) << 4) + rbase + r;
        const int ch = o0 + chl;
        const float inv = IB[ch], bias = IB[512 + ch];
        #pragma unroll
        for (int nx = 0; nx < 2; ++nx) {
          const bool sp = (acc[oy][nx][r] * inv + bias >= 2.0f);
          Fb[chl*68 + ((ntb + nx) << 4) + cl] = sp ? 1.0f : 0.0f;
        }
      }
    __syncthreads();
    const int row = t >> 2, seg = (t & 3) << 4;
    float* dst = outf + ((size_t)tb*CD + o0 + row)*ND + n0 + seg;
    #pragma unroll
    for (int u = 0; u < 4; ++u)
      *(float4*)(dst + 4*u) = *(float4*)&Fb[row*68 + seg + 4*u];
  } else {
    u16* Sb = smem;             // [64][136] f16 spikes
    #pragma unroll
    for (int oy = 0; oy < 2; ++oy)
      #pragma unroll
      for (int r = 0; r < 4; ++r) {
        const int chl = ((otb + oy) << 4) + rbase + r;
        const int ch = o0 + chl;
        const float inv = IB[ch], bias = IB[512 + ch];
        #pragma unroll
        for (int nx = 0; nx < 2; ++nx) {
          const bool sp = (acc[oy][nx][r] * inv + bias >= 2.0f);
          Sb[chl*136 + ((ntb + nx) << 4) + cl] = sp ? (u16)0x3C00 : (u16)0;
        }
      }
    __syncthreads();
    if (br == 0) {
      // transposed: QT[tb][n][c] f16
      const int nr = t >> 2, cs = (t & 3) << 4;
      __align__(16) u16 h[16];
      #pragma unroll
      for (int j = 0; j < 16; ++j) h[j] = Sb[(cs + j)*136 + nr];
      u16* dst = qt + ((size_t)tb*ND + n0 + nr)*CD + o0 + cs;
      *(uint4*)dst       = *(uint4*)&h[0];
      *(uint4*)(dst + 8) = *(uint4*)&h[8];
    } else {
      // direct: K/V [tb][c][n] f16
      u16* sp_ = spk + (size_t)(br - 1)*PLANE;
      const int row = t >> 2, seg = (t & 3) << 4;
      u16* dst = sp_ + ((size_t)tb*CD + o0 + row)*ND + n0 + seg;
      *(uint4*)dst       = *(uint4*)&Sb[row*136 + seg];
      *(uint4*)(dst + 8) = *(uint4*)&Sb[row*136 + seg + 8];
    }
  }
}

// ---------------------------------------------------------------------------
// MFMA attention (all exact): G = K·V^T (f16 mfma, integers <=512, exact),
// o' = Gt-frags x QT (f16 mfma, <=16384 exact), spike = o' >= 8.
// 512 blocks = (tbh, n-chunk 128). Each wave computes full G redundantly.
// Output: S2T[tb][n][c] bf16 spikes for the final bf16 gemm.
// ---------------------------------------------------------------------------
__global__ __launch_bounds__(256) void attn(
    const u16* __restrict__ Qt, const u16* __restrict__ Ks,
    const u16* __restrict__ Vs, u16* __restrict__ S2T)
{
  const int tbh = blockIdx.x >> 2;
  const int n0  = (blockIdx.x & 3) << 7;
  const int t = threadIdx.x, lane = t & 63, wave = t >> 6;
  const int tb = tbh >> 4, h = tbh & 15;

  __shared__ __align__(16) u16 Kt[2*8*512];    // [dt][kc][512], one k-half
  __shared__ __align__(16) u16 Vt[2*8*512];
  __shared__ __align__(16) u16 QTs[8*512];     // [nt][512]
  __shared__ __align__(16) u16 Gt[4*32*40];    // per-wave Gt[d][dp]
  __shared__ __align__(16) u16 Sb[128*40];     // [n_local][c_local] bf16

  const u16* Kh = Ks + (size_t)tbh*32*ND;
  const u16* Vh = Vs + (size_t)tbh*32*ND;

  const int lr = lane >> 2;
  const int lc = ((lane & 3) ^ ((lane >> 3) & 3)) << 3;
  const int fo = ((lane & 15) << 5) + ((((lane >> 4) ^ ((lane >> 1) & 3)) & 3) << 3);

  f32x4 g[2][2];
  const f32x4 zero = {0.f, 0.f, 0.f, 0.f};
  g[0][0] = zero; g[0][1] = zero; g[1][0] = zero; g[1][1] = zero;

  for (int half = 0; half < 2; ++half) {
    if (half) __syncthreads();               // waves done reading prev half
    #pragma unroll
    for (int j = 0; j < 8; ++j) {
      const int u = wave*8 + j;              // 0..31
      const int mat = u >> 4, dt = (u >> 3) & 1, kc = u & 7;
      const u16* src = (mat ? Vh : Kh) + (size_t)((dt << 4) + lr)*ND + (half << 8) + (kc << 5) + lc;
      u16* dst = (mat ? Vt : Kt) + (((dt << 3) + kc) << 9) + (lane << 3);
      async_ld16(src, dst);
    }
    if (half == 0) {
      #pragma unroll
      for (int j = 0; j < 2; ++j) {
        const int nt = wave*2 + j;
        async_ld16(Qt + ((size_t)tb*ND + n0 + (nt << 4) + lr)*CD + (h << 5) + lc,
                   QTs + (nt << 9) + (lane << 3));
      }
    }
    __syncthreads();
    for (int kc = 0; kc < 8; ++kc) {
      const f16* kt = (const f16*)Kt;
      const f16* vt = (const f16*)Vt;
      f16x8 ka0 = *(const f16x8*)(kt + (kc << 9) + fo);
      f16x8 ka1 = *(const f16x8*)(kt + ((8 + kc) << 9) + fo);
      f16x8 vb0 = *(const f16x8*)(vt + (kc << 9) + fo);
      f16x8 vb1 = *(const f16x8*)(vt + ((8 + kc) << 9) + fo);
      g[0][0] = __builtin_amdgcn_mfma_f32_16x16x32_f16(ka0, vb0, g[0][0], 0,0,0);
      g[0][1] = __builtin_amdgcn_mfma_f32_16x16x32_f16(ka0, vb1, g[0][1], 0,0,0);
      g[1][0] = __builtin_amdgcn_mfma_f32_16x16x32_f16(ka1, vb0, g[1][0], 0,0,0);
      g[1][1] = __builtin_amdgcn_mfma_f32_16x16x32_f16(ka1, vb1, g[1][1], 0,0,0);
    }
  }

  // per-wave Gt[d][dp] = G[dp][d]  (f16 exact, integers <=512)
  f16* myG = (f16*)(Gt + wave*(32*40));
  const int rq = (lane >> 4) << 2, cl = lane & 15;
  #pragma unroll
  for (int d1t = 0; d1t < 2; ++d1t)
    #pragma unroll
    for (int d2t = 0; d2t < 2; ++d2t)
      #pragma unroll
      for (int r = 0; r < 4; ++r) {
        const int d1 = (d1t << 4) + rq + r;       // row of G
        const int d2 = (d2t << 4) + cl;           // col of G
        myG[d2*40 + d1] = (f16)g[d1t][d2t][r];
      }
  asm volatile("s_waitcnt lgkmcnt(0)" ::: "memory");

  // phase 2: o'[d][n] = sum_dp Gt[d][dp] * QT[n][dp]
  f32x4 o[2][2];
  o[0][0] = zero; o[0][1] = zero; o[1][0] = zero; o[1][1] = zero;
  const f16* qs = (const f16*)QTs;
  #pragma unroll
  for (int dd = 0; dd < 2; ++dd) {
    f16x8 ga = *(const f16x8*)(myG + (((dd << 4) + cl)*40) + ((lane >> 4) << 3));
    #pragma unroll
    for (int ntl = 0; ntl < 2; ++ntl) {
      f16x8 qb = *(const f16x8*)(qs + ((wave*2 + ntl) << 9) + fo);
      o[dd][ntl] = __builtin_amdgcn_mfma_f32_16x16x32_f16(ga, qb, o[dd][ntl], 0,0,0);
    }
  }

  // spikes -> Sb (bf16), per-wave-disjoint n rows, then coalesced store
  #pragma unroll
  for (int dd = 0; dd < 2; ++dd)
    #pragma unroll
    for (int ntl = 0; ntl < 2; ++ntl)
      #pragma unroll
      for (int r = 0; r < 4; ++r) {
        const int n_local = ((wave*2 + ntl) << 4) + cl;
        const int c_local = (dd << 4) + rq + r;
        Sb[n_local*40 + c_local] = (o[dd][ntl][r] >= 8.0f) ? (u16)0x3F80 : (u16)0;
      }
  asm volatile("s_waitcnt lgkmcnt(0)" ::: "memory");

  const int nr = (wave << 5) + (lane >> 1);
  const int cs = (lane & 1) << 4;
  u16* dst = S2T + ((size_t)tb*ND + n0 + nr)*CD + (h << 5) + cs;
  *(uint4*)dst       = *(uint4*)&Sb[nr*40 + cs];
  *(uint4*)(dst + 8) = *(uint4*)&Sb[nr*40 + cs + 8];
}

// ---------------------------------------------------------------------------
extern "C" void kernel_launch(void* const* d_in, const int* in_sizes, int n_in,
                              void* d_out, int out_size, void* d_ws, size_t ws_size,
                              hipStream_t stream)
{
  const float* x  = (const float*)d_in[0];
  const float* y  = (const float*)d_in[1];
  const float* qw = (const float*)d_in[2];
  const float* qg = (const float*)d_in[3];
  const float* qb = (const float*)d_in[4];
  const float* qm = (const float*)d_in[5];
  const float* qv = (const float*)d_in[6];
  const float* kw = (const float*)d_in[7];
  const float* kg = (const float*)d_in[8];
  const float* kb = (const float*)d_in[9];
  const float* km = (const float*)d_in[10];
  const float* kv = (const float*)d_in[11];
  const float* vw = (const float*)d_in[12];
  const float* vg = (const float*)d_in[13];
  const float* vb = (const float*)d_in[14];
  const float* vm = (const float*)d_in[15];
  const float* vv = (const float*)d_in[16];
  const float* pw = (const float*)d_in[17];
  const float* pg = (const float*)d_in[18];
  const float* pb = (const float*)d_in[19];
  const float* pm = (const float*)d_in[20];
  const float* pv = (const float*)d_in[21];

  u16* wsu = (u16*)d_ws;
  // layout (u16): xT[3] | yT[3] | W[4][3] | QT | Kspk | Vspk | S2T | ib(f32)
  u16* Wq   = wsu + (size_t)6*PLANE;
  u16* QT   = wsu + (size_t)6*PLANE + 12*WPL;
  u16* Kspk = QT + (size_t)PLANE;
  u16* S2T  = QT + (size_t)3*PLANE;
  float* ib = (float*)(QT + (size_t)4*PLANE);

  prep<<<2056, 256, 0, stream>>>(x, y, qw, kw, vw, pw,
      qg, qb, qm, qv, kg, kb, km, kv, vg, vb, vm, vv, pg, pb, pm, pv,
      wsu, ib);

  gemm_mfma<3><<<1536, 256, 0, stream>>>(Wq, wsu, ib, QT, Kspk, nullptr);

  attn<<<512, 256, 0, stream>>>(QT, Kspk, Kspk + (size_t)PLANE, S2T);

  gemm_mfma<1><<<512, 256, 0, stream>>>(Wq + (size_t)9*WPL, S2T,
      ib + 3*1024, nullptr, nullptr, (float*)d_out);
}

// Round 5
// 170.771 us; speedup vs baseline: 1.6711x; 1.0279x over previous
//
#include <hip/hip_runtime.h>
#include <math.h>

#define TBD 8
#define CD  512
#define ND  512
#define PLANE (TBD*CD*ND)   // 2,097,152 elems (u16) per plane
#define WPL   (CD*CD)

typedef unsigned short u16;
typedef unsigned int u32;
typedef _Float16 f16;
typedef __attribute__((ext_vector_type(8))) short bf16x8;
typedef __attribute__((ext_vector_type(8))) _Float16 f16x8;
typedef __attribute__((ext_vector_type(4))) float f32x4;

__device__ __forceinline__ float b2f(u16 u){
  union{u32 i; float f;} x; x.i = ((u32)u) << 16; return x.f;
}
__device__ __forceinline__ u16 f2b(float f){
  u32 u = __builtin_bit_cast(u32, f);
  u += 0x7fffu + ((u >> 16) & 1u);
  return (u16)(u >> 16);
}
__device__ __forceinline__ void async_ld16(const void* g, void* l){
  __builtin_amdgcn_global_load_lds((const __attribute__((address_space(1))) u32*)g,
      (__attribute__((address_space(3))) u32*)l, 16, 0, 0);
}

// ---------------------------------------------------------------------------
// prep (r3/r4-proven, unchanged):
//  [0,1024):   x/y -> 3 exact bf16 split planes each, transposed to [tb][n][c]
//  [1024,2048): 4 W matrices -> 3 bf16 split planes [o][c]
//  [2048,2056): BN inv/bias
// ---------------------------------------------------------------------------
__global__ __launch_bounds__(256) void prep(
    const float* __restrict__ x, const float* __restrict__ y,
    const float* __restrict__ Qw, const float* __restrict__ Kw,
    const float* __restrict__ Vw, const float* __restrict__ Pw,
    const float* __restrict__ Qg, const float* __restrict__ Qb, const float* __restrict__ Qm, const float* __restrict__ Qv,
    const float* __restrict__ Kg, const float* __restrict__ Kb, const float* __restrict__ Km, const float* __restrict__ Kv,
    const float* __restrict__ Vg, const float* __restrict__ Vb, const float* __restrict__ Vm, const float* __restrict__ Vv,
    const float* __restrict__ Pg, const float* __restrict__ Pb, const float* __restrict__ Pm, const float* __restrict__ Pv,
    u16* __restrict__ wsu, float* __restrict__ ib)
{
  const int bx = blockIdx.x, t = threadIdx.x;
  if (bx < 1024) {
    __shared__ __align__(16) float tl[64][68];
    const int inp = bx >> 9, rem = bx & 511;
    const int tb = rem >> 6, tile = rem & 63;
    const int ct = (tile & 7) << 6, nt = (tile >> 3) << 6;
    const float* xg = inp ? y : x;
    #pragma unroll
    for (int r = 0; r < 4; ++r) {
      const int row = (t >> 4) + (r << 4);
      const int col = (t & 15) << 2;
      *(float4*)&tl[row][col] =
          *(const float4*)(xg + ((size_t)(tb*CD + ct + row))*ND + nt + col);
    }
    __syncthreads();
    const int nl = t >> 2, cb = (t & 3) << 4;
    __align__(16) u16 h[3][16];
    #pragma unroll
    for (int j = 0; j < 16; ++j) {
      const float f = tl[cb + j][nl];
      const u16 a = f2b(f);  const float r1 = f - b2f(a);
      const u16 b = f2b(r1); const float r2 = r1 - b2f(b);
      h[0][j] = a; h[1][j] = b; h[2][j] = f2b(r2);
    }
    u16* base = wsu + (size_t)inp*3*PLANE;
    const size_t rowo = ((size_t)tb*ND + nt + nl)*CD + ct + cb;
    #pragma unroll
    for (int s = 0; s < 3; ++s) {
      *(uint4*)(base + (size_t)s*PLANE + rowo)     = *(uint4*)&h[s][0];
      *(uint4*)(base + (size_t)s*PLANE + rowo + 8) = *(uint4*)&h[s][8];
    }
  } else if (bx < 2048) {
    const int b2 = bx - 1024;
    const int mat = b2 >> 8, rr = b2 & 255;
    const float* Wg = (mat==0)?Qw:(mat==1)?Kw:(mat==2)?Vw:Pw;
    const int row = (rr << 1) + (t >> 7);
    const int col = (t & 127) << 2;
    const float4 w = *(const float4*)(Wg + (size_t)row*CD + col);
    const float f[4] = {w.x, w.y, w.z, w.w};
    __align__(8) u16 h[3][4];
    #pragma unroll
    for (int j = 0; j < 4; ++j) {
      const u16 a = f2b(f[j]);  const float r1 = f[j] - b2f(a);
      const u16 b = f2b(r1);    const float r2 = r1 - b2f(b);
      h[0][j] = a; h[1][j] = b; h[2][j] = f2b(r2);
    }
    u16* base = wsu + (size_t)6*PLANE + (size_t)mat*3*WPL;
    #pragma unroll
    for (int s = 0; s < 3; ++s)
      *(uint2*)(base + (size_t)s*WPL + (size_t)row*CD + col) = *(uint2*)&h[s][0];
  } else {
    const int idx = (bx - 2048)*256 + t;
    const int br = idx >> 9, ch = idx & 511;
    const float* G = (br==0)?Qg:(br==1)?Kg:(br==2)?Vg:Pg;
    const float* B = (br==0)?Qb:(br==1)?Kb:(br==2)?Vb:Pb;
    const float* M = (br==0)?Qm:(br==1)?Km:(br==2)?Vm:Pm;
    const float* V = (br==0)?Qv:(br==1)?Kv:(br==2)?Vv:Pv;
    const float inv = G[ch] / sqrtf(V[ch] + 1e-5f);
    ib[br*1024 + ch]       = inv;
    ib[br*1024 + 512 + ch] = B[ch] - M[ch]*inv;
  }
}

// ---------------------------------------------------------------------------
// Split-bf16 MFMA GEMM + BN + LIF.  r3-proven main loop AND r3-proven
// direct-scatter epilogue (the r4 LDS-bounce epilogue cost +13.3 us:
// block-lifetime barriers + 8-way-conflicted transpose gather).
//  XS=3 (qkv fused): outputs Q/K/V spikes as f16, layout [tb][c][n].
//  XS=1 (final):     fp32 spikes -> outf [tb][c][n].
// ---------------------------------------------------------------------------
template<int XS>
__global__ __launch_bounds__(256) void gemm_mfma(
    const u16* __restrict__ Ab, const u16* __restrict__ Bbp,
    const float* __restrict__ ibp,
    u16* __restrict__ spk, float* __restrict__ outf)
{
  const int bx  = blockIdx.x;
  const int idx = bx & 511;
  const int br  = bx >> 9;
  const int tb  = idx & 7;
  const int o0  = ((idx >> 3) & 7) << 6;
  const int n0  = (idx >> 6) << 6;
  const int t    = threadIdx.x;
  const int lane = t & 63, wave = t >> 6;

  const u16* A = Ab + (size_t)br*3*WPL;
  const u16* B = Bbp + (size_t)(br ? 3 : 0)*PLANE;
  const float* IB = ibp + br*1024;

  __shared__ __align__(16) u16 smem[2*3*4*512 + 2*XS*4*512];
  u16* Al = smem;                       // [buf][s][ot][512]
  u16* Bl = smem + 2*3*4*512;           // [buf][s][nt][512]

  const int lr = lane >> 2;
  const int lc = ((lane & 3) ^ ((lane >> 3) & 3)) << 3;
  constexpr int TPW = (12 + 4*XS) / 4;

  auto stage = [&](int buf, int c0) {
    #pragma unroll
    for (int j = 0; j < TPW; ++j) {
      const int tix = wave*TPW + j;
      if (tix < 12) {
        const int s = tix >> 2, ot = tix & 3;
        async_ld16(A + (size_t)s*WPL + (size_t)(o0 + (ot<<4) + lr)*CD + c0 + lc,
                   Al + (((buf*3 + s)*4 + ot) << 9) + (lane << 3));
      } else {
        const int k = tix - 12, s = k >> 2, nt = k & 3;
        async_ld16(B + (size_t)s*PLANE + ((size_t)tb*ND + n0 + (nt<<4) + lr)*CD + c0 + lc,
                   Bl + (((buf*XS + s)*4 + nt) << 9) + (lane << 3));
      }
    }
  };

  f32x4 acc[2][2];
  const f32x4 zero = {0.f, 0.f, 0.f, 0.f};
  acc[0][0] = zero; acc[0][1] = zero; acc[1][0] = zero; acc[1][1] = zero;

  const int otb = (wave >> 1) << 1;
  const int ntb = (wave & 1) << 1;
  const int fo = ((lane & 15) << 5) + ((((lane >> 4) ^ ((lane >> 1) & 3)) & 3) << 3);

  stage(0, 0);
  for (int i = 0; i < 16; ++i) {
    const int buf = i & 1;
    __syncthreads();
    if (i < 15) stage(buf ^ 1, (i + 1) << 5);

    bf16x8 Af[3][2], Bf[XS][2];
    #pragma unroll
    for (int s = 0; s < 3; ++s)
      #pragma unroll
      for (int oy = 0; oy < 2; ++oy)
        Af[s][oy] = *(const bf16x8*)(Al + (((buf*3 + s)*4 + otb + oy) << 9) + fo);
    #pragma unroll
    for (int s = 0; s < XS; ++s)
      #pragma unroll
      for (int nx = 0; nx < 2; ++nx)
        Bf[s][nx] = *(const bf16x8*)(Bl + (((buf*XS + s)*4 + ntb + nx) << 9) + fo);

    auto mm = [&](int sa, int sb) {
      #pragma unroll
      for (int oy = 0; oy < 2; ++oy)
        #pragma unroll
        for (int nx = 0; nx < 2; ++nx)
          acc[oy][nx] = __builtin_amdgcn_mfma_f32_16x16x32_bf16(
              Af[sa][oy], Bf[sb][nx], acc[oy][nx], 0, 0, 0);
    };
    if constexpr (XS == 3) {
      mm(0,0); mm(0,1); mm(1,0); mm(1,1); mm(0,2); mm(2,0);
    } else {
      mm(0,0); mm(1,0); mm(2,0);
    }
  }

  // ---- r3-proven direct-scatter epilogue: BN + LIF ----
  // C layout (m89): col=lane&15, row=(lane>>4)*4+reg
  const int rbase = (lane >> 4) << 2;
  const int cl = lane & 15;
  #pragma unroll
  for (int oy = 0; oy < 2; ++oy) {
    #pragma unroll
    for (int r = 0; r < 4; ++r) {
      const int ch = o0 + ((otb + oy) << 4) + rbase + r;
      const float inv  = IB[ch];
      const float bias = IB[512 + ch];
      #pragma unroll
      for (int nx = 0; nx < 2; ++nx) {
        const bool sp = (acc[oy][nx][r] * inv + bias >= 2.0f);
        const int n = n0 + ((ntb + nx) << 4) + cl;
        const size_t off = ((size_t)tb*CD + ch)*ND + n;
        if constexpr (XS == 1) outf[off] = sp ? 1.0f : 0.0f;
        else spk[(size_t)br*PLANE + off] = sp ? (u16)0x3C00 : (u16)0;
      }
    }
  }
}

// ---------------------------------------------------------------------------
// MFMA attention (all exact): G = K·V^T (f16 mfma, integers <=512 exact),
// o' = Gt x Q (f16 mfma, <=16384 exact fp32), spike = o' >= 8.
// 512 blocks = (tbh, n-chunk 128).  Q/K/V all [tb][c][n] f16 (no transpose
// needed from the gemm).  Q is staged into a group-padded LDS layout
// (group = 4 dp-rows x 128 n, group stride 520 u16 = 260 words ≡ 4 mod 32)
// so phase-2 B-fragment column gathers are bank-conflict-free (2/bank).
// Output: S2T[tb][n][c] bf16 spikes for the final bf16 gemm.
// ---------------------------------------------------------------------------
__global__ __launch_bounds__(256) void attn(
    const u16* __restrict__ Qs, const u16* __restrict__ Ks,
    const u16* __restrict__ Vs, u16* __restrict__ S2T)
{
  const int tbh = blockIdx.x >> 2;
  const int n0  = (blockIdx.x & 3) << 7;
  const int t = threadIdx.x, lane = t & 63, wave = t >> 6;
  const int tb = tbh >> 4, h = tbh & 15;

  __shared__ __align__(16) u16 Kt[2*8*512];    // [dt][kc][512], one m-half
  __shared__ __align__(16) u16 Vt[2*8*512];
  __shared__ __align__(16) u16 Qg[8*520];      // 8 groups of 4 dp-rows x 128 n
  __shared__ __align__(16) u16 Gt[4*32*40];    // per-wave Gt[d][dp]
  __shared__ __align__(16) u16 Sb[128*40];     // [n_local][c_local] bf16

  const u16* Kh = Ks + (size_t)tbh*32*ND;
  const u16* Vh = Vs + (size_t)tbh*32*ND;
  const u16* Qh = Qs + (size_t)tbh*32*ND;

  const int lr = lane >> 2;
  const int lc = ((lane & 3) ^ ((lane >> 3) & 3)) << 3;
  const int fo = ((lane & 15) << 5) + ((((lane >> 4) ^ ((lane >> 1) & 3)) & 3) << 3);

  f32x4 g[2][2];
  const f32x4 zero = {0.f, 0.f, 0.f, 0.f};
  g[0][0] = zero; g[0][1] = zero; g[1][0] = zero; g[1][1] = zero;

  for (int half = 0; half < 2; ++half) {
    if (half) __syncthreads();               // waves done reading prev half
    #pragma unroll
    for (int j = 0; j < 8; ++j) {
      const int u = wave*8 + j;              // 0..31
      const int mat = u >> 4, dt = (u >> 3) & 1, kc = u & 7;
      const u16* src = (mat ? Vh : Kh) + (size_t)((dt << 4) + lr)*ND + (half << 8) + (kc << 5) + lc;
      u16* dst = (mat ? Vt : Kt) + (((dt << 3) + kc) << 9) + (lane << 3);
      async_ld16(src, dst);
    }
    if (half == 0) {
      // stage Q: group g covers dp rows 4g..4g+3, all 128 n of this chunk
      #pragma unroll
      for (int j = 0; j < 2; ++j) {
        const int gq = wave*2 + j;
        async_ld16(Qh + (size_t)((gq << 2) + (lane >> 4))*ND + n0 + ((lane & 15) << 3),
                   Qg + gq*520 + (lane << 3));
      }
    }
    __syncthreads();
    for (int kc = 0; kc < 8; ++kc) {
      const f16* kt = (const f16*)Kt;
      const f16* vt = (const f16*)Vt;
      f16x8 ka0 = *(const f16x8*)(kt + (kc << 9) + fo);
      f16x8 ka1 = *(const f16x8*)(kt + ((8 + kc) << 9) + fo);
      f16x8 vb0 = *(const f16x8*)(vt + (kc << 9) + fo);
      f16x8 vb1 = *(const f16x8*)(vt + ((8 + kc) << 9) + fo);
      g[0][0] = __builtin_amdgcn_mfma_f32_16x16x32_f16(ka0, vb0, g[0][0], 0,0,0);
      g[0][1] = __builtin_amdgcn_mfma_f32_16x16x32_f16(ka0, vb1, g[0][1], 0,0,0);
      g[1][0] = __builtin_amdgcn_mfma_f32_16x16x32_f16(ka1, vb0, g[1][0], 0,0,0);
      g[1][1] = __builtin_amdgcn_mfma_f32_16x16x32_f16(ka1, vb1, g[1][1], 0,0,0);
    }
  }

  // per-wave Gt[d][dp] = G[dp][d]  (f16 exact, integers <=512)
  f16* myG = (f16*)(Gt + wave*(32*40));
  const int rq = (lane >> 4) << 2, cl = lane & 15;
  #pragma unroll
  for (int d1t = 0; d1t < 2; ++d1t)
    #pragma unroll
    for (int d2t = 0; d2t < 2; ++d2t)
      #pragma unroll
      for (int r = 0; r < 4; ++r) {
        const int d1 = (d1t << 4) + rq + r;       // row of G
        const int d2 = (d2t << 4) + cl;           // col of G
        myG[d2*40 + d1] = (f16)g[d1t][d2t][r];
      }
  asm volatile("s_waitcnt lgkmcnt(0)" ::: "memory");

  // phase 2: o'[d][n] = sum_dp Gt[d][dp] * Q[dp][n]
  // B-frag for n-tile: lane (n16=lane&15, kg=lane>>4) gathers Q[kg*8+j][n]
  // from Qg: word bank = (g*4 + n16/2) % 32 -> kg-disjoint 8-bank ranges.
  f32x4 o[2][2];
  o[0][0] = zero; o[0][1] = zero; o[1][0] = zero; o[1][1] = zero;
  const f16* ql = (const f16*)Qg;
  const int kg = lane >> 4, n16 = lane & 15;
  #pragma unroll
  for (int ntl = 0; ntl < 2; ++ntl) {
    const int n0w = ((wave << 1) + ntl) << 4;
    f16x8 qb;
    #pragma unroll
    for (int j = 0; j < 8; ++j)
      qb[j] = ql[(2*kg + (j >> 2))*520 + (j & 3)*128 + n0w + n16];
    #pragma unroll
    for (int dd = 0; dd < 2; ++dd) {
      f16x8 ga = *(const f16x8*)(myG + (((dd << 4) + cl)*40) + (kg << 3));
      o[dd][ntl] = __builtin_amdgcn_mfma_f32_16x16x32_f16(ga, qb, o[dd][ntl], 0,0,0);
    }
  }

  // spikes -> Sb (bf16), per-wave-disjoint n rows, then coalesced store
  #pragma unroll
  for (int dd = 0; dd < 2; ++dd)
    #pragma unroll
    for (int ntl = 0; ntl < 2; ++ntl)
      #pragma unroll
      for (int r = 0; r < 4; ++r) {
        const int n_local = ((wave*2 + ntl) << 4) + cl;
        const int c_local = (dd << 4) + rq + r;
        Sb[n_local*40 + c_local] = (o[dd][ntl][r] >= 8.0f) ? (u16)0x3F80 : (u16)0;
      }
  asm volatile("s_waitcnt lgkmcnt(0)" ::: "memory");

  const int nr = (wave << 5) + (lane >> 1);
  const int cs = (lane & 1) << 4;
  u16* dst = S2T + ((size_t)tb*ND + n0 + nr)*CD + (h << 5) + cs;
  *(uint4*)dst       = *(uint4*)&Sb[nr*40 + cs];
  *(uint4*)(dst + 8) = *(uint4*)&Sb[nr*40 + cs + 8];
}

// ---------------------------------------------------------------------------
extern "C" void kernel_launch(void* const* d_in, const int* in_sizes, int n_in,
                              void* d_out, int out_size, void* d_ws, size_t ws_size,
                              hipStream_t stream)
{
  const float* x  = (const float*)d_in[0];
  const float* y  = (const float*)d_in[1];
  const float* qw = (const float*)d_in[2];
  const float* qg = (const float*)d_in[3];
  const float* qb = (const float*)d_in[4];
  const float* qm = (const float*)d_in[5];
  const float* qv = (const float*)d_in[6];
  const float* kw = (const float*)d_in[7];
  const float* kg = (const float*)d_in[8];
  const float* kb = (const float*)d_in[9];
  const float* km = (const float*)d_in[10];
  const float* kv = (const float*)d_in[11];
  const float* vw = (const float*)d_in[12];
  const float* vg = (const float*)d_in[13];
  const float* vb = (const float*)d_in[14];
  const float* vm = (const float*)d_in[15];
  const float* vv = (const float*)d_in[16];
  const float* pw = (const float*)d_in[17];
  const float* pg = (const float*)d_in[18];
  const float* pb = (const float*)d_in[19];
  const float* pm = (const float*)d_in[20];
  const float* pv = (const float*)d_in[21];

  u16* wsu = (u16*)d_ws;
  // layout (u16): xT[3] | yT[3] | W[4][3] | Q,K,V spikes [c][n] | S2T | ib
  u16* Wq   = wsu + (size_t)6*PLANE;
  u16* SPK  = wsu + (size_t)6*PLANE + 12*WPL;
  u16* S2T  = SPK + (size_t)3*PLANE;
  float* ib = (float*)(SPK + (size_t)4*PLANE);

  prep<<<2056, 256, 0, stream>>>(x, y, qw, kw, vw, pw,
      qg, qb, qm, qv, kg, kb, km, kv, vg, vb, vm, vv, pg, pb, pm, pv,
      wsu, ib);

  gemm_mfma<3><<<1536, 256, 0, stream>>>(Wq, wsu, ib, SPK, nullptr);

  attn<<<512, 256, 0, stream>>>(SPK, SPK + (size_t)PLANE, SPK + 2*(size_t)PLANE, S2T);

  gemm_mfma<1><<<512, 256, 0, stream>>>(Wq + (size_t)9*WPL, S2T,
      ib + 3*1024, nullptr, (float*)d_out);
}